// Round 3
// baseline (273.328 us; speedup 1.0000x reference)
//
#include <hip/hip_runtime.h>
#include <math.h>

// Steerable CNP target prediction — separable-RBF factorization.
//
// out[t,c] = (sum_i Kx[t,i] * sum_j Ky[t,j] * FMc[j,i]) / (Sx[t]*Sy[t])
// Kx[t,i] = exp(-(xt0 - ax[i])^2 / (2 l^2)), channels 2,3 softplus'd first.
//
// Round 3: 8 waves/block (wave = channel x j-half), TT=8, 1024 blocks
//  -> 32 waves/CU (hw max) for latency hiding. Target VGPR <= 64.

#define NA      128
#define TT      8     // targets per block -> 1024 blocks
#define THREADS 512   // 8 waves: wid&3 = channel, wid>>2 = j-half

// ---------- pre-kernel: softplus(FM[2:4]) -> sp (2*128*128 floats) ----------
__global__ __launch_bounds__(256)
void softplus_pre(const float* __restrict__ fm, float* __restrict__ sp)
{
    const int idx = blockIdx.x * 256 + threadIdx.x;          // float4 index
    const int n4  = 2 * NA * NA / 4;                         // 8192
    if (idx >= n4) return;
    float4 v = reinterpret_cast<const float4*>(fm + 2 * NA * NA)[idx];
    v.x = (v.x > 15.0f) ? v.x : log1pf(__expf(v.x));
    v.y = (v.y > 15.0f) ? v.y : log1pf(__expf(v.y));
    v.z = (v.z > 15.0f) ? v.z : log1pf(__expf(v.z));
    v.w = (v.w > 15.0f) ? v.w : log1pf(__expf(v.w));
    reinterpret_cast<float4*>(sp)[idx] = v;
}

// ---------- main kernel ----------
__global__ __launch_bounds__(THREADS, 8)
void cnp_main(const float* __restrict__ fm,    // [4][NA][NA]
              const float* __restrict__ sp,    // [2][NA][NA] softplus'd c2,c3
              const float* __restrict__ grid,  // [NA*NA][2]
              const float* __restrict__ xt,    // [T][2]
              const float* __restrict__ lsp,   // [1]
              float* __restrict__ out,         // means [T][2] then sigmas [T][2]
              int n_target, int use_sp)
{
    __shared__ __attribute__((aligned(16))) float Kx[TT * NA];
    __shared__ __attribute__((aligned(16))) float Ky[TT * NA];
    __shared__ float red[4][2][TT];   // (channel, j-half, target)
    __shared__ float sxy[2][TT];

    const int tid  = threadIdx.x;
    const int wid  = tid >> 6;        // 0..7
    const int c    = wid & 3;         // channel
    const int jq2  = wid >> 2;        // j-half of the wave (0/1)
    const int lane = tid & 63;
    const int jh   = lane >> 5;       // j-quarter bit within wave
    const int ig   = lane & 31;       // i-group
    const int i4   = ig * 4;          // this thread's 4 i-columns
    const int t0   = blockIdx.x * TT;

    const float l      = lsp[0];
    const float inv2l2 = 0.5f / (l * l);

    // ---- phase 0: separable kernel rows into LDS ----
    // grid[g] = (ax[g>>7], ax[g&127])  =>  ax[j] = grid[j*2+1]
    for (int k = tid; k < TT * NA; k += THREADS) {
        const int t = k >> 7;
        const int j = k & 127;
        const int tg = t0 + t;
        const float ax = grid[j * 2 + 1];
        const float dx = xt[tg * 2 + 0] - ax;
        const float dy = xt[tg * 2 + 1] - ax;
        Kx[k] = __expf(-dx * dx * inv2l2);
        Ky[k] = __expf(-dy * dy * inv2l2);
    }
    __syncthreads();

    // ---- phase 1: V[t][4i] = sum_{j in my quarter} Ky[t,j]*FMc[j,i] ----
    const float* src = (c < 2 || !use_sp) ? (fm + c * NA * NA)
                                          : (sp + (c - 2) * NA * NA);
    const bool do_sp_inline = (!use_sp) && (c >= 2);

    float4 v0, v1, v2, v3, v4, v5, v6, v7;
    v0 = v1 = v2 = v3 = v4 = v5 = v6 = v7 = make_float4(0.f, 0.f, 0.f, 0.f);

    const int j0 = (jq2 * 2 + jh) * 32;       // 32-row j window per (wave, jh)
    const float* base = src + j0 * NA + i4;

#pragma unroll 2
    for (int g = 0; g < 8; ++g) {
        const int jj = g * 4;
        float4 f0 = *reinterpret_cast<const float4*>(&base[(jj + 0) * NA]);
        float4 f1 = *reinterpret_cast<const float4*>(&base[(jj + 1) * NA]);
        float4 f2 = *reinterpret_cast<const float4*>(&base[(jj + 2) * NA]);
        float4 f3 = *reinterpret_cast<const float4*>(&base[(jj + 3) * NA]);
        if (do_sp_inline) {   // fallback only if ws too small
#define SP1(z) z = (z > 15.0f) ? z : log1pf(__expf(z))
            SP1(f0.x); SP1(f0.y); SP1(f0.z); SP1(f0.w);
            SP1(f1.x); SP1(f1.y); SP1(f1.z); SP1(f1.w);
            SP1(f2.x); SP1(f2.y); SP1(f2.z); SP1(f2.w);
            SP1(f3.x); SP1(f3.y); SP1(f3.z); SP1(f3.w);
#undef SP1
        }
#define STEP(T, V)                                                             \
        {                                                                      \
            const float4 k4 = *reinterpret_cast<const float4*>(&Ky[(T) * NA + j0 + jj]); \
            V.x = fmaf(k4.x, f0.x, fmaf(k4.y, f1.x, fmaf(k4.z, f2.x, fmaf(k4.w, f3.x, V.x)))); \
            V.y = fmaf(k4.x, f0.y, fmaf(k4.y, f1.y, fmaf(k4.z, f2.y, fmaf(k4.w, f3.y, V.y)))); \
            V.z = fmaf(k4.x, f0.z, fmaf(k4.y, f1.z, fmaf(k4.z, f2.z, fmaf(k4.w, f3.z, V.z)))); \
            V.w = fmaf(k4.x, f0.w, fmaf(k4.y, f1.w, fmaf(k4.z, f2.w, fmaf(k4.w, f3.w, V.w)))); \
        }
        STEP(0, v0) STEP(1, v1) STEP(2, v2) STEP(3, v3)
        STEP(4, v4) STEP(5, v5) STEP(6, v6) STEP(7, v7)
#undef STEP
    }

    // ---- phase 2: 64-lane reduce of Kx[t,i]*V -> red[c][jq2][t] ----
#define RED(T, V)                                                              \
    {                                                                          \
        const float4 kx4 = *reinterpret_cast<const float4*>(&Kx[(T) * NA + i4]); \
        float w = fmaf(kx4.x, V.x, fmaf(kx4.y, V.y, fmaf(kx4.z, V.z, kx4.w * V.w))); \
        w += __shfl_xor(w, 1);  w += __shfl_xor(w, 2);  w += __shfl_xor(w, 4); \
        w += __shfl_xor(w, 8);  w += __shfl_xor(w, 16); w += __shfl_xor(w, 32); \
        if (lane == 0) red[c][jq2][(T)] = w;                                   \
    }
    RED(0, v0) RED(1, v1) RED(2, v2) RED(3, v3)
    RED(4, v4) RED(5, v5) RED(6, v6) RED(7, v7)
#undef RED

    // Sx (jh=0 lanes) / Sy (jh=1 lanes) on wave 0; 32-wide reduce per half
    if (wid == 0) {
        const float* kb = jh ? Ky : Kx;
#define SRED(T)                                                                \
        {                                                                      \
            const float4 q = *reinterpret_cast<const float4*>(&kb[(T) * NA + i4]); \
            float u = (q.x + q.y) + (q.z + q.w);                               \
            u += __shfl_xor(u, 1); u += __shfl_xor(u, 2); u += __shfl_xor(u, 4); \
            u += __shfl_xor(u, 8); u += __shfl_xor(u, 16);                     \
            if (ig == 0) sxy[jh][(T)] = u;                                     \
        }
        SRED(0) SRED(1) SRED(2) SRED(3) SRED(4) SRED(5) SRED(6) SRED(7)
#undef SRED
    }
    __syncthreads();

    // ---- phase 3: combine j-halves, normalize, write (32 outputs) ----
    if (tid < 4 * TT) {
        const int t  = tid & (TT - 1);
        const int cc = tid >> 3;            // requires TT == 8
        const int tg = t0 + t;
        if (tg < n_target) {
            const float numer = red[cc][0][t] + red[cc][1][t];
            const float val = numer / (sxy[0][t] * sxy[1][t]);
            if (cc < 2) out[tg * 2 + cc] = val;                        // means
            else        out[n_target * 2 + tg * 2 + (cc - 2)] = val;   // sigmas
        }
    }
}

extern "C" void kernel_launch(void* const* d_in, const int* in_sizes, int n_in,
                              void* d_out, int out_size, void* d_ws, size_t ws_size,
                              hipStream_t stream) {
    const float* fm   = (const float*)d_in[0];
    const float* grid = (const float*)d_in[1];
    const float* xt   = (const float*)d_in[2];
    const float* lsp  = (const float*)d_in[3];
    float* out = (float*)d_out;
    float* sp  = (float*)d_ws;

    const int n_target = in_sizes[2] / 2;                 // 8192
    const size_t sp_bytes = (size_t)2 * NA * NA * sizeof(float);
    const int use_sp = (ws_size >= sp_bytes) ? 1 : 0;

    if (use_sp) {
        const int n4 = 2 * NA * NA / 4;                   // 8192 float4s
        hipLaunchKernelGGL(softplus_pre, dim3((n4 + 255) / 256), dim3(256), 0, stream,
                           fm, sp);
    }
    const int blocks = (n_target + TT - 1) / TT;          // 1024
    hipLaunchKernelGGL(cnp_main, dim3(blocks), dim3(THREADS), 0, stream,
                       fm, sp, grid, xt, lsp, out, n_target, use_sp);
}

// Round 4
// 33.959 us; speedup vs baseline: 8.0489x; 8.0489x over previous
//
#include <hip/hip_runtime.h>
#include <math.h>

// Steerable CNP target prediction — separable-RBF factorization.
//
// out[t,c] = (sum_i Kx[t,i] * sum_j Ky[t,j] * FMc[j,i]) / (Sx[t]*Sy[t])
// Kx[t,i] = exp(-(xt0 - ax[i])^2 / (2 l^2)), channels 2,3 softplus'd first.
//
// Round 4: wave = channel; lane = (jsub:2 | ig:4); 8 i-cols/thread so one
// broadcast ds_read_b128 of Ky feeds 32 FMAs (round 2: 16). jsub row-order
// rotation makes the 4-address Ky multicast bank-conflict-free.
// Plain __launch_bounds__(256): round 3 proved forcing occupancy -> spill.

#define NA      128
#define TT      8     // targets per block -> 1024 blocks
#define THREADS 256   // 4 waves; wave == channel

// ---------- pre-kernel: softplus(FM[2:4]) -> sp (2*128*128 floats) ----------
__global__ __launch_bounds__(256)
void softplus_pre(const float* __restrict__ fm, float* __restrict__ sp)
{
    const int idx = blockIdx.x * 256 + threadIdx.x;          // float4 index
    const int n4  = 2 * NA * NA / 4;                         // 8192
    if (idx >= n4) return;
    float4 v = reinterpret_cast<const float4*>(fm + 2 * NA * NA)[idx];
    v.x = (v.x > 15.0f) ? v.x : log1pf(__expf(v.x));
    v.y = (v.y > 15.0f) ? v.y : log1pf(__expf(v.y));
    v.z = (v.z > 15.0f) ? v.z : log1pf(__expf(v.z));
    v.w = (v.w > 15.0f) ? v.w : log1pf(__expf(v.w));
    reinterpret_cast<float4*>(sp)[idx] = v;
}

// ---------- main kernel ----------
__global__ __launch_bounds__(THREADS)
void cnp_main(const float* __restrict__ fm,    // [4][NA][NA]
              const float* __restrict__ sp,    // [2][NA][NA] softplus'd c2,c3
              const float* __restrict__ grid,  // [NA*NA][2]
              const float* __restrict__ xt,    // [T][2]
              const float* __restrict__ lsp,   // [1]
              float* __restrict__ out,         // means [T][2] then sigmas [T][2]
              int n_target, int use_sp)
{
    __shared__ __attribute__((aligned(16))) float Kx[TT * NA];
    __shared__ __attribute__((aligned(16))) float Ky[TT * NA];
    __shared__ float red[4][TT];
    __shared__ float sxy[2][TT];

    const int tid  = threadIdx.x;
    const int c    = tid >> 6;        // wave index == channel
    const int lane = tid & 63;
    const int ig   = lane & 15;       // i-group: 16 groups x 8 cols = 128 i
    const int jsub = lane >> 4;       // j-subrange: 4 groups x 32 rows = 128 j
    const int i8   = ig * 8;
    const int t0   = blockIdx.x * TT;

    const float l      = lsp[0];
    const float inv2l2 = 0.5f / (l * l);

    // ---- phase 0: separable kernel rows into LDS ----
    // grid[g] = (ax[g>>7], ax[g&127])  =>  ax[j] = grid[j*2+1]
    for (int k = tid; k < TT * NA; k += THREADS) {
        const int t = k >> 7;
        const int j = k & 127;
        int tg = t0 + t; if (tg >= n_target) tg = n_target - 1;
        const float ax = grid[j * 2 + 1];
        const float dx = xt[tg * 2 + 0] - ax;
        const float dy = xt[tg * 2 + 1] - ax;
        Kx[k] = __expf(-dx * dx * inv2l2);
        Ky[k] = __expf(-dy * dy * inv2l2);
    }
    __syncthreads();

    // ---- phase 1: per-thread V over (8 i-cols, 32 j-rows, 8 targets) ----
    const float* src = (c < 2 || !use_sp) ? (fm + c * NA * NA)
                                          : (sp + (c - 2) * NA * NA);
    const bool do_sp_inline = (!use_sp) && (c >= 2);

    float4 pA0, pA1, pA2, pA3, pA4, pA5, pA6, pA7;   // i8..i8+3 accumulators
    float4 pB0, pB1, pB2, pB3, pB4, pB5, pB6, pB7;   // i8+4..i8+7
    pA0 = pA1 = pA2 = pA3 = pA4 = pA5 = pA6 = pA7 = make_float4(0.f, 0.f, 0.f, 0.f);
    pB0 = pB1 = pB2 = pB3 = pB4 = pB5 = pB6 = pB7 = make_float4(0.f, 0.f, 0.f, 0.f);

    const int jb = jsub * 32;

#pragma unroll 2
    for (int g = 0; g < 8; ++g) {
        // rotate row-group order per jsub so the 4 Ky multicast addresses
        // land in distinct bank quads (conflict-free)
        const int gg = (g + jsub) & 7;
        const int j  = jb + gg * 4;
        const float* b = src + j * NA + i8;
        float4 fa0 = *reinterpret_cast<const float4*>(b);
        float4 fb0 = *reinterpret_cast<const float4*>(b + 4);
        float4 fa1 = *reinterpret_cast<const float4*>(b + NA);
        float4 fb1 = *reinterpret_cast<const float4*>(b + NA + 4);
        float4 fa2 = *reinterpret_cast<const float4*>(b + 2 * NA);
        float4 fb2 = *reinterpret_cast<const float4*>(b + 2 * NA + 4);
        float4 fa3 = *reinterpret_cast<const float4*>(b + 3 * NA);
        float4 fb3 = *reinterpret_cast<const float4*>(b + 3 * NA + 4);
        if (do_sp_inline) {   // fallback only if ws too small
#define SP1(z) z = (z > 15.0f) ? z : log1pf(__expf(z))
            SP1(fa0.x); SP1(fa0.y); SP1(fa0.z); SP1(fa0.w);
            SP1(fb0.x); SP1(fb0.y); SP1(fb0.z); SP1(fb0.w);
            SP1(fa1.x); SP1(fa1.y); SP1(fa1.z); SP1(fa1.w);
            SP1(fb1.x); SP1(fb1.y); SP1(fb1.z); SP1(fb1.w);
            SP1(fa2.x); SP1(fa2.y); SP1(fa2.z); SP1(fa2.w);
            SP1(fb2.x); SP1(fb2.y); SP1(fb2.z); SP1(fb2.w);
            SP1(fa3.x); SP1(fa3.y); SP1(fa3.z); SP1(fa3.w);
            SP1(fb3.x); SP1(fb3.y); SP1(fb3.z); SP1(fb3.w);
#undef SP1
        }
#define STEP(T, PA, PB)                                                        \
        {                                                                      \
            const float4 k4 = *reinterpret_cast<const float4*>(&Ky[(T) * NA + j]); \
            PA.x = fmaf(k4.x, fa0.x, fmaf(k4.y, fa1.x, fmaf(k4.z, fa2.x, fmaf(k4.w, fa3.x, PA.x)))); \
            PA.y = fmaf(k4.x, fa0.y, fmaf(k4.y, fa1.y, fmaf(k4.z, fa2.y, fmaf(k4.w, fa3.y, PA.y)))); \
            PA.z = fmaf(k4.x, fa0.z, fmaf(k4.y, fa1.z, fmaf(k4.z, fa2.z, fmaf(k4.w, fa3.z, PA.z)))); \
            PA.w = fmaf(k4.x, fa0.w, fmaf(k4.y, fa1.w, fmaf(k4.z, fa2.w, fmaf(k4.w, fa3.w, PA.w)))); \
            PB.x = fmaf(k4.x, fb0.x, fmaf(k4.y, fb1.x, fmaf(k4.z, fb2.x, fmaf(k4.w, fb3.x, PB.x)))); \
            PB.y = fmaf(k4.x, fb0.y, fmaf(k4.y, fb1.y, fmaf(k4.z, fb2.y, fmaf(k4.w, fb3.y, PB.y)))); \
            PB.z = fmaf(k4.x, fb0.z, fmaf(k4.y, fb1.z, fmaf(k4.z, fb2.z, fmaf(k4.w, fb3.z, PB.z)))); \
            PB.w = fmaf(k4.x, fb0.w, fmaf(k4.y, fb1.w, fmaf(k4.z, fb2.w, fmaf(k4.w, fb3.w, PB.w)))); \
        }
        STEP(0, pA0, pB0) STEP(1, pA1, pB1) STEP(2, pA2, pB2) STEP(3, pA3, pB3)
        STEP(4, pA4, pB4) STEP(5, pA5, pB5) STEP(6, pA6, pB6) STEP(7, pA7, pB7)
#undef STEP
    }

    // ---- phase 2: apply Kx, 64-lane reduce (covers ig AND jsub) ----
#define RED(T, PA, PB)                                                         \
    {                                                                          \
        const float4 ka = *reinterpret_cast<const float4*>(&Kx[(T) * NA + i8]);     \
        const float4 kb = *reinterpret_cast<const float4*>(&Kx[(T) * NA + i8 + 4]); \
        float w = fmaf(ka.x, PA.x, fmaf(ka.y, PA.y, fmaf(ka.z, PA.z, fmaf(ka.w, PA.w, \
                  fmaf(kb.x, PB.x, fmaf(kb.y, PB.y, fmaf(kb.z, PB.z, kb.w * PB.w))))))); \
        w += __shfl_xor(w, 1);  w += __shfl_xor(w, 2);  w += __shfl_xor(w, 4); \
        w += __shfl_xor(w, 8);  w += __shfl_xor(w, 16); w += __shfl_xor(w, 32); \
        if (lane == 0) red[c][(T)] = w;                                        \
    }
    RED(0, pA0, pB0) RED(1, pA1, pB1) RED(2, pA2, pB2) RED(3, pA3, pB3)
    RED(4, pA4, pB4) RED(5, pA5, pB5) RED(6, pA6, pB6) RED(7, pA7, pB7)
#undef RED

    // ---- Sx on wave 0, Sy on wave 1 (4x duplicate over jsub -> *0.25) ----
    if (c < 2) {
        const float* kb0 = c ? Ky : Kx;
#define SRED(T)                                                                \
        {                                                                      \
            const float4 qa = *reinterpret_cast<const float4*>(&kb0[(T) * NA + i8]);     \
            const float4 qb = *reinterpret_cast<const float4*>(&kb0[(T) * NA + i8 + 4]); \
            float u = ((qa.x + qa.y) + (qa.z + qa.w)) + ((qb.x + qb.y) + (qb.z + qb.w)); \
            u += __shfl_xor(u, 1);  u += __shfl_xor(u, 2);  u += __shfl_xor(u, 4); \
            u += __shfl_xor(u, 8);  u += __shfl_xor(u, 16); u += __shfl_xor(u, 32); \
            if (lane == 0) sxy[c][(T)] = u * 0.25f;                            \
        }
        SRED(0) SRED(1) SRED(2) SRED(3) SRED(4) SRED(5) SRED(6) SRED(7)
#undef SRED
    }
    __syncthreads();

    // ---- phase 3: normalize + write (32 outputs per block) ----
    if (tid < 4 * TT) {
        const int t  = tid & (TT - 1);
        const int cc = tid >> 3;            // requires TT == 8
        const int tg = t0 + t;
        if (tg < n_target) {
            const float val = red[cc][t] / (sxy[0][t] * sxy[1][t]);
            if (cc < 2) out[tg * 2 + cc] = val;                        // means
            else        out[n_target * 2 + tg * 2 + (cc - 2)] = val;   // sigmas
        }
    }
}

extern "C" void kernel_launch(void* const* d_in, const int* in_sizes, int n_in,
                              void* d_out, int out_size, void* d_ws, size_t ws_size,
                              hipStream_t stream) {
    const float* fm   = (const float*)d_in[0];
    const float* grid = (const float*)d_in[1];
    const float* xt   = (const float*)d_in[2];
    const float* lsp  = (const float*)d_in[3];
    float* out = (float*)d_out;
    float* sp  = (float*)d_ws;

    const int n_target = in_sizes[2] / 2;                 // 8192
    const size_t sp_bytes = (size_t)2 * NA * NA * sizeof(float);
    const int use_sp = (ws_size >= sp_bytes) ? 1 : 0;

    if (use_sp) {
        const int n4 = 2 * NA * NA / 4;                   // 8192 float4s
        hipLaunchKernelGGL(softplus_pre, dim3((n4 + 255) / 256), dim3(256), 0, stream,
                           fm, sp);
    }
    const int blocks = (n_target + TT - 1) / TT;          // 1024
    hipLaunchKernelGGL(cnp_main, dim3(blocks), dim3(THREADS), 0, stream,
                       fm, sp, grid, xt, lsp, out, n_target, use_sp);
}

// Round 5
// 32.461 us; speedup vs baseline: 8.4202x; 1.0461x over previous
//
#include <hip/hip_runtime.h>
#include <math.h>

// Steerable CNP target prediction — separable-RBF factorization.
//
// out[t,c] = (sum_i Kx[t,i] * sum_j Ky[t,j] * FMc[j,i]) / (Sx[t]*Sy[t])
// Kx[t,i] = exp(-(xt0 - ax[i])^2 / (2 l^2)), channels 2,3 softplus'd first.
//
// Round 5 = round-2 structure (best: 28.9us) + register double-buffer
// prefetch of the FM global loads (hide ~200cyc L2 latency under the
// 128 FMAs of the current iteration). Round 3/4 lesson: keep VGPR < 128.

#define NA      128
#define TT      8     // targets per block -> 1024 blocks
#define THREADS 256   // 4 waves; wave == channel; lane: jh=lane>>5, ig=lane&31

// ---------- pre-kernel: softplus(FM[2:4]) -> sp (2*128*128 floats) ----------
__global__ __launch_bounds__(256)
void softplus_pre(const float* __restrict__ fm, float* __restrict__ sp)
{
    const int idx = blockIdx.x * 256 + threadIdx.x;          // float4 index
    const int n4  = 2 * NA * NA / 4;                         // 8192
    if (idx >= n4) return;
    float4 v = reinterpret_cast<const float4*>(fm + 2 * NA * NA)[idx];
    v.x = (v.x > 15.0f) ? v.x : log1pf(__expf(v.x));
    v.y = (v.y > 15.0f) ? v.y : log1pf(__expf(v.y));
    v.z = (v.z > 15.0f) ? v.z : log1pf(__expf(v.z));
    v.w = (v.w > 15.0f) ? v.w : log1pf(__expf(v.w));
    reinterpret_cast<float4*>(sp)[idx] = v;
}

// ---------- main kernel ----------
__global__ __launch_bounds__(THREADS)
void cnp_main(const float* __restrict__ fm,    // [4][NA][NA]
              const float* __restrict__ sp,    // [2][NA][NA] softplus'd c2,c3
              const float* __restrict__ grid,  // [NA*NA][2]
              const float* __restrict__ xt,    // [T][2]
              const float* __restrict__ lsp,   // [1]
              float* __restrict__ out,         // means [T][2] then sigmas [T][2]
              int n_target, int use_sp)
{
    __shared__ __attribute__((aligned(16))) float Kx[TT * NA];
    __shared__ __attribute__((aligned(16))) float Ky[TT * NA];
    __shared__ float red[4][TT];
    __shared__ float sxy[2][TT];

    const int tid  = threadIdx.x;
    const int c    = tid >> 6;        // wave index == channel
    const int lane = tid & 63;
    const int jh   = lane >> 5;       // which j-half this lane sums
    const int ig   = lane & 31;       // i-group
    const int i4   = ig * 4;          // this thread's 4 i-columns
    const int t0   = blockIdx.x * TT;

    const float l      = lsp[0];
    const float inv2l2 = 0.5f / (l * l);

    // ---- phase 0: separable kernel rows into LDS ----
    // grid[g] = (ax[g>>7], ax[g&127])  =>  ax[j] = grid[j*2+1]
    for (int k = tid; k < TT * NA; k += THREADS) {
        const int t = k >> 7;
        const int j = k & 127;
        const int tg = t0 + t;
        const float ax = grid[j * 2 + 1];
        const float dx = xt[tg * 2 + 0] - ax;
        const float dy = xt[tg * 2 + 1] - ax;
        Kx[k] = __expf(-dx * dx * inv2l2);
        Ky[k] = __expf(-dy * dy * inv2l2);
    }
    __syncthreads();

    // ---- phase 1: V[t][4i] = sum_{j in my half} Ky[t,j]*FMc[j,i] ----
    const float* src = (c < 2 || !use_sp) ? (fm + c * NA * NA)
                                          : (sp + (c - 2) * NA * NA);
    const bool do_sp_inline = (!use_sp) && (c >= 2);

    float4 v0, v1, v2, v3, v4, v5, v6, v7;
    v0 = v1 = v2 = v3 = v4 = v5 = v6 = v7 = make_float4(0.f, 0.f, 0.f, 0.f);

    const int jb0 = jh * 64;
    const float* base = src + jb0 * NA + i4;

    // prefetch g=0
    float4 f0 = *reinterpret_cast<const float4*>(&base[0 * NA]);
    float4 f1 = *reinterpret_cast<const float4*>(&base[1 * NA]);
    float4 f2 = *reinterpret_cast<const float4*>(&base[2 * NA]);
    float4 f3 = *reinterpret_cast<const float4*>(&base[3 * NA]);

#define SPALL()                                                                \
        if (do_sp_inline) {                                                    \
            /* fallback only if ws too small */                                \
            f0.x = (f0.x > 15.0f) ? f0.x : log1pf(__expf(f0.x));               \
            f0.y = (f0.y > 15.0f) ? f0.y : log1pf(__expf(f0.y));               \
            f0.z = (f0.z > 15.0f) ? f0.z : log1pf(__expf(f0.z));               \
            f0.w = (f0.w > 15.0f) ? f0.w : log1pf(__expf(f0.w));               \
            f1.x = (f1.x > 15.0f) ? f1.x : log1pf(__expf(f1.x));               \
            f1.y = (f1.y > 15.0f) ? f1.y : log1pf(__expf(f1.y));               \
            f1.z = (f1.z > 15.0f) ? f1.z : log1pf(__expf(f1.z));               \
            f1.w = (f1.w > 15.0f) ? f1.w : log1pf(__expf(f1.w));               \
            f2.x = (f2.x > 15.0f) ? f2.x : log1pf(__expf(f2.x));               \
            f2.y = (f2.y > 15.0f) ? f2.y : log1pf(__expf(f2.y));               \
            f2.z = (f2.z > 15.0f) ? f2.z : log1pf(__expf(f2.z));               \
            f2.w = (f2.w > 15.0f) ? f2.w : log1pf(__expf(f2.w));               \
            f3.x = (f3.x > 15.0f) ? f3.x : log1pf(__expf(f3.x));               \
            f3.y = (f3.y > 15.0f) ? f3.y : log1pf(__expf(f3.y));               \
            f3.z = (f3.z > 15.0f) ? f3.z : log1pf(__expf(f3.z));               \
            f3.w = (f3.w > 15.0f) ? f3.w : log1pf(__expf(f3.w));               \
        }

#define STEP(T, V, JJ)                                                         \
        {                                                                      \
            const float4 k4 = *reinterpret_cast<const float4*>(&Ky[(T) * NA + jb0 + (JJ)]); \
            V.x = fmaf(k4.x, f0.x, fmaf(k4.y, f1.x, fmaf(k4.z, f2.x, fmaf(k4.w, f3.x, V.x)))); \
            V.y = fmaf(k4.x, f0.y, fmaf(k4.y, f1.y, fmaf(k4.z, f2.y, fmaf(k4.w, f3.y, V.y)))); \
            V.z = fmaf(k4.x, f0.z, fmaf(k4.y, f1.z, fmaf(k4.z, f2.z, fmaf(k4.w, f3.z, V.z)))); \
            V.w = fmaf(k4.x, f0.w, fmaf(k4.y, f1.w, fmaf(k4.z, f2.w, fmaf(k4.w, f3.w, V.w)))); \
        }

#pragma unroll 3
    for (int g = 0; g < 15; ++g) {
        const int jj = g * 4;
        // issue next iteration's loads BEFORE consuming this one's
        const float* nb = base + (jj + 4) * NA;
        float4 n0 = *reinterpret_cast<const float4*>(&nb[0 * NA]);
        float4 n1 = *reinterpret_cast<const float4*>(&nb[1 * NA]);
        float4 n2 = *reinterpret_cast<const float4*>(&nb[2 * NA]);
        float4 n3 = *reinterpret_cast<const float4*>(&nb[3 * NA]);
        SPALL()
        STEP(0, v0, jj) STEP(1, v1, jj) STEP(2, v2, jj) STEP(3, v3, jj)
        STEP(4, v4, jj) STEP(5, v5, jj) STEP(6, v6, jj) STEP(7, v7, jj)
        f0 = n0; f1 = n1; f2 = n2; f3 = n3;
    }
    {   // peeled last iteration (g = 15)
        const int jj = 60;
        SPALL()
        STEP(0, v0, jj) STEP(1, v1, jj) STEP(2, v2, jj) STEP(3, v3, jj)
        STEP(4, v4, jj) STEP(5, v5, jj) STEP(6, v6, jj) STEP(7, v7, jj)
    }
#undef STEP
#undef SPALL

    // ---- phase 2: numer[t,c] = 64-lane reduce of Kx[t,i]*V ----
#define RED(T, V)                                                              \
    {                                                                          \
        const float4 kx4 = *reinterpret_cast<const float4*>(&Kx[(T) * NA + i4]); \
        float w = fmaf(kx4.x, V.x, fmaf(kx4.y, V.y, fmaf(kx4.z, V.z, kx4.w * V.w))); \
        w += __shfl_xor(w, 1);  w += __shfl_xor(w, 2);  w += __shfl_xor(w, 4); \
        w += __shfl_xor(w, 8);  w += __shfl_xor(w, 16); w += __shfl_xor(w, 32); \
        if (lane == 0) red[c][(T)] = w;                                        \
    }
    RED(0, v0) RED(1, v1) RED(2, v2) RED(3, v3)
    RED(4, v4) RED(5, v5) RED(6, v6) RED(7, v7)
#undef RED

    // Sx (jh=0 lanes) / Sy (jh=1 lanes) on the c==0 wave; 32-wide reduce
    if (c == 0) {
        const float* kb = jh ? Ky : Kx;
#define SRED(T)                                                                \
        {                                                                      \
            const float4 q = *reinterpret_cast<const float4*>(&kb[(T) * NA + i4]); \
            float u = (q.x + q.y) + (q.z + q.w);                               \
            u += __shfl_xor(u, 1); u += __shfl_xor(u, 2); u += __shfl_xor(u, 4); \
            u += __shfl_xor(u, 8); u += __shfl_xor(u, 16);                     \
            if (ig == 0) sxy[jh][(T)] = u;                                     \
        }
        SRED(0) SRED(1) SRED(2) SRED(3) SRED(4) SRED(5) SRED(6) SRED(7)
#undef SRED
    }
    __syncthreads();

    // ---- phase 3: normalize + write (32 outputs per block) ----
    if (tid < 4 * TT) {
        const int t  = tid & (TT - 1);
        const int cc = tid >> 3;            // requires TT == 8
        const int tg = t0 + t;
        if (tg < n_target) {
            const float val = red[cc][t] / (sxy[0][t] * sxy[1][t]);
            if (cc < 2) out[tg * 2 + cc] = val;                        // means
            else        out[n_target * 2 + tg * 2 + (cc - 2)] = val;   // sigmas
        }
    }
}

extern "C" void kernel_launch(void* const* d_in, const int* in_sizes, int n_in,
                              void* d_out, int out_size, void* d_ws, size_t ws_size,
                              hipStream_t stream) {
    const float* fm   = (const float*)d_in[0];
    const float* grid = (const float*)d_in[1];
    const float* xt   = (const float*)d_in[2];
    const float* lsp  = (const float*)d_in[3];
    float* out = (float*)d_out;
    float* sp  = (float*)d_ws;

    const int n_target = in_sizes[2] / 2;                 // 8192
    const size_t sp_bytes = (size_t)2 * NA * NA * sizeof(float);
    const int use_sp = (ws_size >= sp_bytes) ? 1 : 0;

    if (use_sp) {
        const int n4 = 2 * NA * NA / 4;                   // 8192 float4s
        hipLaunchKernelGGL(softplus_pre, dim3((n4 + 255) / 256), dim3(256), 0, stream,
                           fm, sp);
    }
    const int blocks = (n_target + TT - 1) / TT;          // 1024
    hipLaunchKernelGGL(cnp_main, dim3(blocks), dim3(THREADS), 0, stream,
                       fm, sp, grid, xt, lsp, out, n_target, use_sp);
}